// Round 12
// baseline (72.699 us; speedup 1.0000x reference)
//
#include <hip/hip_runtime.h>
#include <cstdint>

#define NTOK 16384

typedef float f4 __attribute__((ext_vector_type(4)));
typedef __attribute__((ext_vector_type(4))) float f32x4;
typedef __attribute__((ext_vector_type(8))) short bf16x8;

__device__ __forceinline__ float readlane_f(float v, int lane) {
  return __int_as_float(__builtin_amdgcn_readlane(__float_as_int(v), lane));
}

__device__ __forceinline__ float wave_sum64(float v) {
  #pragma unroll
  for (int s = 1; s < 64; s <<= 1) v += __shfl_xor(v, s, 64);
  return v;
}

__device__ __forceinline__ float half_sum32(float v) {
  #pragma unroll
  for (int s = 1; s < 32; s <<= 1) v += __shfl_xor(v, s, 64);
  return v;
}

__device__ __forceinline__ uint32_t rne_bf16(float f) {
  uint32_t u = __float_as_uint(f);
  return (u + 0x7FFFu + ((u >> 16) & 1u)) >> 16;   // round-nearest-even bf16
}

// ---------------------------------------------------------------------------
// K1: projections (MFMA) + gates + h/n outputs + kvif side-channel.
// Identical to R11 minus the c-store burst; per token writes k(scaled,biased),
// iv = i*v, ft into SoA buffers in d_ws (8.5MB total).
// ---------------------------------------------------------------------------
__global__ void __launch_bounds__(512, 2)
proj_kernel(const float* __restrict__ x,
            const float* __restrict__ c_prev,
            const float* __restrict__ n_prev,
            const float* __restrict__ w_q, const float* __restrict__ b_q,
            const float* __restrict__ w_k, const float* __restrict__ b_k,
            const float* __restrict__ w_v, const float* __restrict__ b_v,
            const float* __restrict__ w_i, const float* __restrict__ b_i,
            const float* __restrict__ w_f, const float* __restrict__ b_f,
            const float* __restrict__ w_o, const float* __restrict__ b_o,
            float* __restrict__ h_out,
            float* __restrict__ n_out,
            float* __restrict__ k_buf,
            float* __restrict__ iv_buf,
            float* __restrict__ ft_buf)
{
  __shared__ uint32_t smem[16384];   // 64KB: wT bf16 (phase A) -> Y f32 (phase B)
  __shared__ float    cp[64][65];    // c_prev, stride 65 (2-way banks = free)
  __shared__ float    hbuf[4096];
  __shared__ float    nbuf[4096];
  const int tid  = threadIdx.x;
  const int lane = tid & 63;
  const int wid  = tid >> 6;
  const int T0   = blockIdx.x * 64;

  // ---- stage wT[n][k] as bf16 pairs, unit-swizzled ----
  {
    const int n   = tid & 255;
    const int col = n & 63;
    const float* W = (n < 128) ? ((n < 64) ? w_q : w_k)
                               : ((n < 192) ? w_v : w_o);
    const int kph = tid >> 8;
    #pragma unroll
    for (int it = 0; it < 32; ++it) {
      const int kp = it * 2 + kph;
      const float a = W[(2 * kp)     * 64 + col];
      const float b = W[(2 * kp + 1) * 64 + col];
      const uint32_t pk = rne_bf16(a) | (rne_bf16(b) << 16);
      const int unit = (n << 4) + ((kp >> 2) ^ (n & 15));
      smem[(unit << 2) + (kp & 3)] = pk;
    }
  }
  for (int idx = tid; idx < 4096; idx += 512)
    cp[idx >> 6][idx & 63] = c_prev[idx];

  const f4* xp = (const f4*)(x + (size_t)(T0 + wid * 8) * 128);
  f4 xc[4];
  xc[0] = xp[lane];
  xc[1] = xp[64 + lane];
  xc[2] = xp[128 + lane];
  xc[3] = xp[192 + lane];

  __syncthreads();

  // ---- phase A: MFMA projections ----
  const int mt  = wid & 3;
  const int ntg = (wid >> 2) * 8;
  bf16x8 afrag[4];
  {
    const float* xr = x + (size_t)(T0 + mt * 16 + (lane & 15)) * 128
                        + ((lane >> 4) * 8);
    #pragma unroll
    for (int ks = 0; ks < 4; ++ks) {
      const f4 lo = *(const f4*)(xr + ks * 32);
      const f4 hi = *(const f4*)(xr + ks * 32 + 4);
      union { uint32_t u[4]; bf16x8 v; } cv;
      cv.u[0] = rne_bf16(lo.x) | (rne_bf16(lo.y) << 16);
      cv.u[1] = rne_bf16(lo.z) | (rne_bf16(lo.w) << 16);
      cv.u[2] = rne_bf16(hi.x) | (rne_bf16(hi.y) << 16);
      cv.u[3] = rne_bf16(hi.z) | (rne_bf16(hi.w) << 16);
      afrag[ks] = cv.v;
    }
  }
  f32x4 acc[8];
  #pragma unroll
  for (int j = 0; j < 8; ++j) acc[j] = (f32x4){0.f, 0.f, 0.f, 0.f};
  {
    const int bsub = lane & 15, bh = lane >> 4;
    #pragma unroll
    for (int nti = 0; nti < 8; ++nti) {
      const int n = (ntg + nti) * 16 + bsub;
      #pragma unroll
      for (int ks = 0; ks < 4; ++ks) {
        const int unit = (n << 4) + ((ks * 4 + bh) ^ (n & 15));
        const bf16x8 bfrag = *(const bf16x8*)&smem[unit << 2];
        acc[nti] = __builtin_amdgcn_mfma_f32_16x16x32_bf16(afrag[ks], bfrag,
                                                           acc[nti], 0, 0, 0);
      }
    }
  }
  __syncthreads();
  {
    float* y = (float*)smem;                // Y[64][256] f32
    const int trow = mt * 16 + (lane >> 4) * 4;
    const int fcol = lane & 15;
    #pragma unroll
    for (int nti = 0; nti < 8; ++nti) {
      const int f = (ntg + nti) * 16 + fcol;
      #pragma unroll
      for (int r = 0; r < 4; ++r)
        y[(trow + r) * 256 + f] = acc[nti][r];
    }
  }
  __syncthreads();

  // ---- gates in full f32 ----
  float itv[8], ftv[8];
  {
    const int dbase = (lane & 31) << 2;
    const f4 wi4 = *(const f4*)&w_i[dbase];
    const f4 wf4 = *(const f4*)&w_f[dbase];
    const float sbi = b_i[0], sbf = b_f[0];
    #pragma unroll
    for (int c = 0; c < 4; ++c) {
      float pi = xc[c].x * wi4.x + xc[c].y * wi4.y + xc[c].z * wi4.z + xc[c].w * wi4.w;
      float pf = xc[c].x * wf4.x + xc[c].y * wf4.y + xc[c].z * wf4.z + xc[c].w * wf4.w;
      pi = half_sum32(pi);
      pf = half_sum32(pf);
      itv[2 * c]     = __expf(readlane_f(pi, 0)  + sbi);
      itv[2 * c + 1] = __expf(readlane_f(pi, 32) + sbi);
      ftv[2 * c]     = 1.0f / (1.0f + __expf(-(readlane_f(pf, 0)  + sbf)));
      ftv[2 * c + 1] = 1.0f / (1.0f + __expf(-(readlane_f(pf, 32) + sbf)));
    }
  }

  // ---- phase B: reductions + h/n + kvif side-channel (no c stores) ----
  const float bq = b_q[lane], bk = b_k[lane], bv = b_v[lane], bo = b_o[lane];
  const float npv = n_prev[lane];
  const float* y  = (const float*)smem;

  #pragma unroll 1
  for (int tt = 0; tt < 8; ++tt) {
    const int    tl = wid * 8 + tt;
    const size_t t  = (size_t)(T0 + tl);
    const float q   = y[tl * 256 + lane] + bq;
    const float k   = (y[tl * 256 + 64 + lane] + bk) * 0.125f;   // 1/sqrt(64)
    const float v   = y[tl * 256 + 128 + lane] + bv;
    const float oz  = y[tl * 256 + 192 + lane] + bo;
    const float it_ = itv[tt];
    const float ft_ = ftv[tt];

    // kvif side-channel (coalesced 256B stores)
    k_buf[t * 64 + lane]  = k;
    iv_buf[t * 64 + lane] = it_ * v;
    if (lane == 0) ft_buf[t] = ft_;

    const float n_val = fmaf(ft_, npv, it_ * k);
    nbuf[tl * 64 + lane] = n_val;

    const float nq = wave_sum64(n_val * q);
    const float kq = wave_sum64(k * q);

    float c0 = 0.f, c1 = 0.f, c2 = 0.f, c3 = 0.f;
    #pragma unroll
    for (int j = 0; j < 16; ++j) {
      const f4 r4 = *(const f4*)&cp[lane][4 * j];
      c0 = fmaf(r4.x, readlane_f(q, 4 * j),     c0);
      c1 = fmaf(r4.y, readlane_f(q, 4 * j + 1), c1);
      c2 = fmaf(r4.z, readlane_f(q, 4 * j + 2), c2);
      c3 = fmaf(r4.w, readlane_f(q, 4 * j + 3), c3);
    }
    const float cpq = (c0 + c1) + (c2 + c3);

    const float o    = 1.0f / (1.0f + __expf(-oz));
    const float inv  = 1.0f / fmaxf(fabsf(nq), 1.0f);
    const float htil = fmaf(ft_, cpq, it_ * v * kq) * inv;
    hbuf[tl * 64 + lane] = o * htil;
  }

  // ---- bulk h/n stores ----
  {
    const float* hb = hbuf + wid * 512 + lane * 8;
    const float* nb = nbuf + wid * 512 + lane * 8;
    const size_t base = (size_t)(T0 + wid * 8) * 64 + lane * 8;
    f4 h0 = {hb[0], hb[1], hb[2], hb[3]};
    f4 h1 = {hb[4], hb[5], hb[6], hb[7]};
    f4 n0 = {nb[0], nb[1], nb[2], nb[3]};
    f4 n1 = {nb[4], nb[5], nb[6], nb[7]};
    *(f4*)(h_out + base)     = h0;
    *(f4*)(h_out + base + 4) = h1;
    *(f4*)(n_out + base)     = n0;
    *(f4*)(n_out + base + 4) = n1;
  }
}

// ---------------------------------------------------------------------------
// K2: c expansion with the FILL KERNEL'S exact global addressing: one linear
// grid-stride sweep over all 16.7M f4 elements of c_out. At any instant the
// in-flight stores of all resident waves tile ONE contiguous ~8MB region that
// marches linearly (vs 2048 private scattered streams in the fused variants).
// Reads are tiny and cache-hot: cp = 16KB table (L1), k/iv slabs consumed by
// 16 consecutive waves (L2).  c[t][r][c] = ft[t]*cp[r][c] + iv[t][r]*k[t][c].
// ---------------------------------------------------------------------------
__global__ void __launch_bounds__(256)
expand_kernel(const float* __restrict__ c_prev,
              const float* __restrict__ k_buf,
              const float* __restrict__ iv_buf,
              const float* __restrict__ ft_buf,
              float* __restrict__ c_out)
{
  const uint32_t nthreads = 2048 * 256;
  uint32_t gid = blockIdx.x * 256 + threadIdx.x;   // f4 index
  f4* __restrict__ out = (f4*)c_out;
  #pragma unroll 4
  for (int it = 0; it < 32; ++it, gid += nthreads) {
    const uint32_t t  = gid >> 10;
    const uint32_t r  = (gid >> 4) & 63;
    const uint32_t c4 = gid & 15;
    const float ft = ft_buf[t];
    const float iv = iv_buf[(t << 6) | r];
    const f4 kk = *(const f4*)&k_buf[(t << 6) | (c4 << 2)];
    const f4 cp = *(const f4*)&c_prev[(r << 6) | (c4 << 2)];
    f4 val;
    val.x = fmaf(ft, cp.x, iv * kk.x);
    val.y = fmaf(ft, cp.y, iv * kk.y);
    val.z = fmaf(ft, cp.z, iv * kk.z);
    val.w = fmaf(ft, cp.w, iv * kk.w);
    out[gid] = val;
  }
}

extern "C" void kernel_launch(void* const* d_in, const int* in_sizes, int n_in,
                              void* d_out, int out_size, void* d_ws, size_t ws_size,
                              hipStream_t stream) {
  const float* x      = (const float*)d_in[0];
  const float* c_prev = (const float*)d_in[1];
  const float* n_prev = (const float*)d_in[2];
  const float* w_q = (const float*)d_in[3];
  const float* b_q = (const float*)d_in[4];
  const float* w_k = (const float*)d_in[5];
  const float* b_k = (const float*)d_in[6];
  const float* w_v = (const float*)d_in[7];
  const float* b_v = (const float*)d_in[8];
  const float* w_i = (const float*)d_in[9];
  const float* b_i = (const float*)d_in[10];
  const float* w_f = (const float*)d_in[11];
  const float* b_f = (const float*)d_in[12];
  const float* w_o = (const float*)d_in[13];
  const float* b_o = (const float*)d_in[14];

  float* h_out = (float*)d_out;               // 1,048,576
  float* c_out = h_out + 1048576;             // 67,108,864
  float* n_out = c_out + 67108864;            // 1,048,576

  float* k_buf  = (float*)d_ws;               // 1,048,576 floats (4MB)
  float* iv_buf = k_buf + 1048576;            // 4MB
  float* ft_buf = iv_buf + 1048576;           // 64KB

  proj_kernel<<<256, 512, 0, stream>>>(x, c_prev, n_prev,
                                       w_q, b_q, w_k, b_k, w_v, b_v,
                                       w_i, b_i, w_f, b_f, w_o, b_o,
                                       h_out, n_out, k_buf, iv_buf, ft_buf);
  expand_kernel<<<2048, 256, 0, stream>>>(c_prev, k_buf, iv_buf, ft_buf, c_out);
}

// Round 13
// 55.655 us; speedup vs baseline: 1.3063x; 1.3063x over previous
//
#include <hip/hip_runtime.h>
#include <cstdint>

#define NTOK 16384

typedef float f4 __attribute__((ext_vector_type(4)));
typedef __attribute__((ext_vector_type(4))) float f32x4;
typedef __attribute__((ext_vector_type(8))) short bf16x8;

__device__ __forceinline__ float readlane_f(float v, int lane) {
  return __int_as_float(__builtin_amdgcn_readlane(__float_as_int(v), lane));
}

__device__ __forceinline__ float wave_sum64(float v) {
  #pragma unroll
  for (int s = 1; s < 64; s <<= 1) v += __shfl_xor(v, s, 64);
  return v;
}

__device__ __forceinline__ float half_sum32(float v) {
  #pragma unroll
  for (int s = 1; s < 32; s <<= 1) v += __shfl_xor(v, s, 64);
  return v;
}

__device__ __forceinline__ uint32_t rne_bf16(float f) {
  uint32_t u = __float_as_uint(f);
  return (u + 0x7FFFu + ((u >> 16) & 1u)) >> 16;   // round-nearest-even bf16
}

// ---------------------------------------------------------------------------
// Fused mLSTM, MFMA projections. Grid 256 x 512 (1 block/CU, 8 waves).
// R13 = R10 restored verbatim (best measured: 55.3us). Plateau evidence:
// nine structurally distinct phase-B variants (NT, occupancy, unroll, reg
// cache, bank-fix, reorder, rotation, purification, split-kernel fill-pattern)
// land 55.3-56.8 or regress; 5.4 TB/s effective on 286 MB compulsory traffic
// is this op's mixed-stream ceiling on gfx950 at this structure.
//  (1) each wave's 16-slice c-sweep is rotated by 2*wid (8 lockstep waves
//      cover 8 distinct 1KB offsets mod 16KB at every instant).
//  (2) h/n stores leave the c-stream: buffered in LDS in-loop, bulk-stored
//      coalesced per wave after the token loop.
// ---------------------------------------------------------------------------
__global__ void __launch_bounds__(512, 2)
fused_kernel(const float* __restrict__ x,
             const float* __restrict__ c_prev,
             const float* __restrict__ n_prev,
             const float* __restrict__ w_q, const float* __restrict__ b_q,
             const float* __restrict__ w_k, const float* __restrict__ b_k,
             const float* __restrict__ w_v, const float* __restrict__ b_v,
             const float* __restrict__ w_i, const float* __restrict__ b_i,
             const float* __restrict__ w_f, const float* __restrict__ b_f,
             const float* __restrict__ w_o, const float* __restrict__ b_o,
             float* __restrict__ h_out,
             float* __restrict__ c_out,
             float* __restrict__ n_out)
{
  __shared__ uint32_t smem[16384];   // 64KB: wT bf16 (phase A) -> Y f32 (phase B)
  __shared__ float    cp[64][68];    // 17KB: c_prev, padded stride
  __shared__ float    hbuf[4096];    // 16KB: h staging (64 tok x 64)
  __shared__ float    nbuf[4096];    // 16KB: n staging
  const int tid  = threadIdx.x;
  const int lane = tid & 63;
  const int wid  = tid >> 6;
  const int T0   = blockIdx.x * 64;

  // ---- stage wT[n][k] as bf16 pairs, unit-swizzled ----
  // unit(n, kb) = n*16 + (kb ^ (n&15)), kb = 16B-block along k (8 bf16)
  {
    const int n   = tid & 255;
    const int col = n & 63;
    const float* W = (n < 128) ? ((n < 64) ? w_q : w_k)
                               : ((n < 192) ? w_v : w_o);
    const int kph = tid >> 8;               // 0 or 1
    #pragma unroll
    for (int it = 0; it < 32; ++it) {
      const int kp = it * 2 + kph;          // k-pair 0..63
      const float a = W[(2 * kp)     * 64 + col];
      const float b = W[(2 * kp + 1) * 64 + col];
      const uint32_t pk = rne_bf16(a) | (rne_bf16(b) << 16);
      const int unit = (n << 4) + ((kp >> 2) ^ (n & 15));
      smem[(unit << 2) + (kp & 3)] = pk;
    }
  }
  for (int idx = tid; idx < 4096; idx += 512)
    cp[idx >> 6][idx & 63] = c_prev[idx];

  // xc chunks for gates: lane l holds x[T0+wid*8+2c+(l>>5)][4*(l&31)+e]
  const f4* xp = (const f4*)(x + (size_t)(T0 + wid * 8) * 128);
  f4 xc[4];
  xc[0] = xp[lane];
  xc[1] = xp[64 + lane];
  xc[2] = xp[128 + lane];
  xc[3] = xp[192 + lane];

  __syncthreads();

  // ---- phase A: MFMA projections ----
  const int mt  = wid & 3;                  // m-tile (16 tokens)
  const int ntg = (wid >> 2) * 8;           // first of 8 n-tiles
  bf16x8 afrag[4];
  {
    const float* xr = x + (size_t)(T0 + mt * 16 + (lane & 15)) * 128
                        + ((lane >> 4) * 8);
    #pragma unroll
    for (int ks = 0; ks < 4; ++ks) {
      const f4 lo = *(const f4*)(xr + ks * 32);
      const f4 hi = *(const f4*)(xr + ks * 32 + 4);
      union { uint32_t u[4]; bf16x8 v; } cv;
      cv.u[0] = rne_bf16(lo.x) | (rne_bf16(lo.y) << 16);
      cv.u[1] = rne_bf16(lo.z) | (rne_bf16(lo.w) << 16);
      cv.u[2] = rne_bf16(hi.x) | (rne_bf16(hi.y) << 16);
      cv.u[3] = rne_bf16(hi.z) | (rne_bf16(hi.w) << 16);
      afrag[ks] = cv.v;
    }
  }
  f32x4 acc[8];
  #pragma unroll
  for (int j = 0; j < 8; ++j) acc[j] = (f32x4){0.f, 0.f, 0.f, 0.f};
  {
    const int bsub = lane & 15, bh = lane >> 4;
    #pragma unroll
    for (int nti = 0; nti < 8; ++nti) {
      const int n = (ntg + nti) * 16 + bsub;
      #pragma unroll
      for (int ks = 0; ks < 4; ++ks) {
        const int unit = (n << 4) + ((ks * 4 + bh) ^ (n & 15));
        const bf16x8 bfrag = *(const bf16x8*)&smem[unit << 2];
        acc[nti] = __builtin_amdgcn_mfma_f32_16x16x32_bf16(afrag[ks], bfrag,
                                                           acc[nti], 0, 0, 0);
      }
    }
  }
  __syncthreads();                          // all wT reads done; region dies
  {
    float* y = (float*)smem;                // Y[64][256] f32, exact 64KB
    const int trow = mt * 16 + (lane >> 4) * 4;
    const int fcol = lane & 15;
    #pragma unroll
    for (int nti = 0; nti < 8; ++nti) {
      const int f = (ntg + nti) * 16 + fcol;
      #pragma unroll
      for (int r = 0; r < 4; ++r)
        y[(trow + r) * 256 + f] = acc[nti][r];
    }
  }
  __syncthreads();

  // ---- gates in full f32 ----
  float itv[8], ftv[8];
  {
    const int dbase = (lane & 31) << 2;
    const f4 wi4 = *(const f4*)&w_i[dbase];
    const f4 wf4 = *(const f4*)&w_f[dbase];
    const float sbi = b_i[0], sbf = b_f[0];
    #pragma unroll
    for (int c = 0; c < 4; ++c) {
      float pi = xc[c].x * wi4.x + xc[c].y * wi4.y + xc[c].z * wi4.z + xc[c].w * wi4.w;
      float pf = xc[c].x * wf4.x + xc[c].y * wf4.y + xc[c].z * wf4.z + xc[c].w * wf4.w;
      pi = half_sum32(pi);
      pf = half_sum32(pf);
      itv[2 * c]     = __expf(readlane_f(pi, 0)  + sbi);
      itv[2 * c + 1] = __expf(readlane_f(pi, 32) + sbi);
      ftv[2 * c]     = 1.0f / (1.0f + __expf(-(readlane_f(pf, 0)  + sbf)));
      ftv[2 * c + 1] = 1.0f / (1.0f + __expf(-(readlane_f(pf, 32) + sbf)));
    }
  }

  // ---- phase B: expand; pure c-store stream, h/n staged in LDS ----
  const float bq = b_q[lane], bk = b_k[lane], bv = b_v[lane], bo = b_o[lane];
  const float npv = n_prev[lane];
  const int   m   = lane & 15;
  const float* y  = (const float*)smem;

  #pragma unroll 1
  for (int tt = 0; tt < 8; ++tt) {
    const int    tl = wid * 8 + tt;
    const size_t t  = (size_t)(T0 + tl);
    const float q   = y[tl * 256 + lane] + bq;
    const float k   = (y[tl * 256 + 64 + lane] + bk) * 0.125f;   // 1/sqrt(64)
    const float v   = y[tl * 256 + 128 + lane] + bv;
    const float o   = 1.0f / (1.0f + __expf(-(y[tl * 256 + 192 + lane] + bo)));
    const float it_ = itv[tt];
    const float ft_ = ftv[tt];

    const float n_val = fmaf(ft_, npv, it_ * k);
    nbuf[tl * 64 + lane] = n_val;

    const float nq = wave_sum64(n_val * q);
    const float kq = wave_sum64(k * q);

    // cpq[lane] = sum_j c_prev[lane][j] * q[j]
    float c0 = 0.f, c1 = 0.f, c2 = 0.f, c3 = 0.f;
    #pragma unroll
    for (int j = 0; j < 16; ++j) {
      const f4 r4 = *(const f4*)&cp[lane][4 * j];
      c0 = fmaf(r4.x, readlane_f(q, 4 * j),     c0);
      c1 = fmaf(r4.y, readlane_f(q, 4 * j + 1), c1);
      c2 = fmaf(r4.z, readlane_f(q, 4 * j + 2), c2);
      c3 = fmaf(r4.w, readlane_f(q, 4 * j + 3), c3);
    }
    const float cpq = (c0 + c1) + (c2 + c3);

    const float inv  = 1.0f / fmaxf(fabsf(nq), 1.0f);
    const float htil = fmaf(ft_, cpq, it_ * v * kq) * inv;
    hbuf[tl * 64 + lane] = o * htil;

    // rotated c-store sweep: wave wid starts at slice 2*wid -> the 8 lockstep
    // waves write 8 distinct 1KB offsets mod 16KB at every instant
    const float iv = it_ * v;
    const float k40 = __shfl(k, 4 * m, 64);
    const float k41 = __shfl(k, 4 * m + 1, 64);
    const float k42 = __shfl(k, 4 * m + 2, 64);
    const float k43 = __shfl(k, 4 * m + 3, 64);
    f4* ct = (f4*)(c_out + t * 4096);
    #pragma unroll
    for (int s = 0; s < 16; ++s) {
      const int ss  = (s + 2 * wid) & 15;
      const int row = 4 * ss + (lane >> 4);
      const float ivr = __shfl(iv, row, 64);
      const f4 c4 = *(const f4*)&cp[row][4 * m];
      f4 val;
      val.x = fmaf(ft_, c4.x, ivr * k40);
      val.y = fmaf(ft_, c4.y, ivr * k41);
      val.z = fmaf(ft_, c4.z, ivr * k42);
      val.w = fmaf(ft_, c4.w, ivr * k43);
      ct[ss * 64 + lane] = val;
    }
  }

  // ---- bulk h/n stores: 2KB contiguous per wave, 2 x dwordx4 per lane ----
  {
    const float* hb = hbuf + wid * 512 + lane * 8;
    const float* nb = nbuf + wid * 512 + lane * 8;
    const size_t base = (size_t)(T0 + wid * 8) * 64 + lane * 8;
    f4 h0 = {hb[0], hb[1], hb[2], hb[3]};
    f4 h1 = {hb[4], hb[5], hb[6], hb[7]};
    f4 n0 = {nb[0], nb[1], nb[2], nb[3]};
    f4 n1 = {nb[4], nb[5], nb[6], nb[7]};
    *(f4*)(h_out + base)     = h0;
    *(f4*)(h_out + base + 4) = h1;
    *(f4*)(n_out + base)     = n0;
    *(f4*)(n_out + base + 4) = n1;
  }
}

extern "C" void kernel_launch(void* const* d_in, const int* in_sizes, int n_in,
                              void* d_out, int out_size, void* d_ws, size_t ws_size,
                              hipStream_t stream) {
  const float* x      = (const float*)d_in[0];
  const float* c_prev = (const float*)d_in[1];
  const float* n_prev = (const float*)d_in[2];
  const float* w_q = (const float*)d_in[3];
  const float* b_q = (const float*)d_in[4];
  const float* w_k = (const float*)d_in[5];
  const float* b_k = (const float*)d_in[6];
  const float* w_v = (const float*)d_in[7];
  const float* b_v = (const float*)d_in[8];
  const float* w_i = (const float*)d_in[9];
  const float* b_i = (const float*)d_in[10];
  const float* w_f = (const float*)d_in[11];
  const float* b_f = (const float*)d_in[12];
  const float* w_o = (const float*)d_in[13];
  const float* b_o = (const float*)d_in[14];

  float* h_out = (float*)d_out;               // 1,048,576
  float* c_out = h_out + 1048576;             // 67,108,864
  float* n_out = c_out + 67108864;            // 1,048,576

  fused_kernel<<<256, 512, 0, stream>>>(x, c_prev, n_prev,
                                        w_q, b_q, w_k, b_k, w_v, b_v,
                                        w_i, b_i, w_f, b_f, w_o, b_o,
                                        h_out, c_out, n_out);
}